// Round 10
// baseline (404.851 us; speedup 1.0000x reference)
//
#include <hip/hip_runtime.h>
#include <hip/hip_bf16.h>
#include <stdint.h>

// fp32 I/O. Conv3x3, 1x1 projections, and attention run as bf16 MFMA.
// Round 16: max-only stats + l-in-pv + zred merge -> 333us. But pv regressed
//   59.8->67.1: lsum adds sat in the barrier-bound P phase (serial chain all
//   waves must drain). Lesson: extra work is free only in the MFMA phase.
// Round 17 (this):
//   - pv: P phase reverted byte-exact to v4; l accumulated in the PV phase
//     from the pb fragments (wave w sums pb[w] -> its 16 rows; 16 cvt+add
//     per step co-issued under 64 MFMA; butterfly over quad at end). l is
//     now the sum of the bf16 P actually used in PV (more consistent).
//   - t256 DELETED: conv epilogue writes Ct[pix][256] bf16 directly (same
//     f2b(y) -> bit-identical Ct for projections); zred reads the conv
//     residual from Ct post-transpose (coalesced bf16x4). Saves ~100MB
//     round-trip; conv's scattered 2B stores cover a 16KB L2 region/block
//     -> full-line HBM writes.

constexpr int CINCH = 512;
constexpr int NPIX  = 4096;   // 64*64

typedef __bf16 bf16x8 __attribute__((ext_vector_type(8)));
typedef __bf16 bf16x4 __attribute__((ext_vector_type(4)));
typedef float  f32x4  __attribute__((ext_vector_type(4)));

__device__ __forceinline__ __bf16 f2b(float f) {
    __hip_bfloat16 h = __float2bfloat16(f);
    return *reinterpret_cast<__bf16*>(&h);
}

__device__ __forceinline__ void load_lds16(const void* g, void* l) {
    __builtin_amdgcn_global_load_lds(
        (const __attribute__((address_space(1))) unsigned int*)(uintptr_t)g,
        (__attribute__((address_space(3))) unsigned int*)(uintptr_t)l,
        16, 0, 0);
}

// ---------------------------------------------------------------------------
// Prep A: conv weights fp32 [oc][ic][9] -> Wt bf16 [mod][tap][oc][ic];
// BN scale/shift tables; zero row. grid 2307 x 256.
// ---------------------------------------------------------------------------
__global__ __launch_bounds__(256)
void prep_w(const float* __restrict__ w_r, const float* __restrict__ w_d,
            const float* __restrict__ cb_r, const float* __restrict__ bg_r,
            const float* __restrict__ bb_r, const float* __restrict__ bm_r,
            const float* __restrict__ bv_r,
            const float* __restrict__ cb_d, const float* __restrict__ bg_d,
            const float* __restrict__ bb_d, const float* __restrict__ bm_d,
            const float* __restrict__ bv_d,
            __bf16* __restrict__ Wt, float* __restrict__ scA,
            float* __restrict__ shB, __bf16* __restrict__ zrow)
{
    const int t = threadIdx.x;
    const int blk = blockIdx.x;
    if (blk < 2304) {
        int gid = blk * 1024 + t * 4;
        int mod = gid >= 1179648;
        int o2  = gid - mod * 1179648;
        int tap = o2 >> 17;
        int r   = o2 & 131071;
        int oc  = r >> 9;
        int ic  = r & 511;
        const float* wsrc = mod ? w_d : w_r;
        long base = ((long)(oc * 512 + ic)) * 9 + tap;
        bf16x4 v;
        v.x = f2b(wsrc[base]);
        v.y = f2b(wsrc[base + 9]);
        v.z = f2b(wsrc[base + 18]);
        v.w = f2b(wsrc[base + 27]);
        *(bf16x4*)&Wt[gid] = v;
    } else if (blk == 2304) {
        unsigned short* z = (unsigned short*)zrow;
        z[t] = 0; z[t + 256] = 0;
    } else {
        int mod = blk - 2305;
        const float* cb = mod ? cb_d : cb_r;
        const float* bg = mod ? bg_d : bg_r;
        const float* bb = mod ? bb_d : bb_r;
        const float* bm = mod ? bm_d : bm_r;
        const float* bv = mod ? bv_d : bv_r;
        int oc = t;
        float sc = bg[oc] * rsqrtf(bv[oc] + 1e-5f);
        scA[mod * 256 + oc] = sc;
        shB[mod * 256 + oc] = (cb[oc] - bm[oc]) * sc + bb[oc];
    }
}

// ---------------------------------------------------------------------------
// Prep B: projection weights fp32 -> bf16. Wq/Wk padded to 128 rows (zeros).
// ---------------------------------------------------------------------------
__global__ __launch_bounds__(256)
void prep_gw(const float* __restrict__ qw_r, const float* __restrict__ qw_d,
             const float* __restrict__ kw_r, const float* __restrict__ kw_d,
             const float* __restrict__ vw_r, const float* __restrict__ vw_d,
             const float* __restrict__ uw_r, const float* __restrict__ uw_d,
             __bf16* __restrict__ Wq, __bf16* __restrict__ Wk,
             __bf16* __restrict__ Wv, __bf16* __restrict__ Wu)
{
    int gid = blockIdx.x * 1024 + threadIdx.x * 4;
    __bf16* dst;
    float4 f = make_float4(0.f, 0.f, 0.f, 0.f);
    if (gid < 65536) {
        int mod = gid >> 15, e = gid & 32767;
        dst = Wq + gid;
        if (e < 8192) f = *(const float4*)((mod ? qw_d : qw_r) + e);
    } else if (gid < 131072) {
        int g = gid - 65536;
        int mod = g >> 15, e = g & 32767;
        dst = Wk + g;
        if (e < 8192) f = *(const float4*)((mod ? kw_d : kw_r) + e);
    } else if (gid < 262144) {
        int g = gid - 131072;
        int mod = g >> 16, e = g & 65535;
        dst = Wv + g;
        f = *(const float4*)((mod ? vw_d : vw_r) + e);
    } else {
        int g = gid - 262144;
        int mod = g >> 17, e = g & 131071;
        dst = Wu + g;
        f = *(const float4*)((mod ? uw_d : uw_r) + e);
    }
    bf16x4 o; o.x = f2b(f.x); o.y = f2b(f.y); o.z = f2b(f.z); o.w = f2b(f.w);
    *(bf16x4*)dst = o;
}

// ---------------------------------------------------------------------------
// Prep C: X fp32 [mod][b][512][4096] -> Xp bf16 [modb][4096pix][512ic]
// ---------------------------------------------------------------------------
__global__ __launch_bounds__(256)
void xpose(const float* __restrict__ inr, const float* __restrict__ ind,
           __bf16* __restrict__ Xp)
{
    __shared__ float tile[32][33];
    const int t = threadIdx.x;
    const int p0 = blockIdx.x * 32;
    const int ic0 = blockIdx.y * 32;
    const int mb = blockIdx.z;
    const int mod = mb >> 1, b = mb & 1;
    const float* src = (mod ? ind : inr) + (long)b * CINCH * NPIX;

    int i = t >> 3, j4 = (t & 7) * 4;
    float4 v = *(const float4*)&src[(long)(ic0 + i) * NPIX + p0 + j4];
    tile[i][j4 + 0] = v.x; tile[i][j4 + 1] = v.y;
    tile[i][j4 + 2] = v.z; tile[i][j4 + 3] = v.w;
    __syncthreads();
    int j = t >> 3, i4 = (t & 7) * 4;
    bf16x4 o;
    o.x = f2b(tile[i4 + 0][j]);
    o.y = f2b(tile[i4 + 1][j]);
    o.z = f2b(tile[i4 + 2][j]);
    o.w = f2b(tile[i4 + 3][j]);
    *(bf16x4*)&Xp[((long)mb * NPIX + p0 + j) * 512 + ic0 + i4] = o;
}

// ---------------------------------------------------------------------------
// Conv3x3 implicit-GEMM MFMA v5 (halo, 8 waves). Same as round 13 except the
// epilogue writes Ct bf16 [pix][256] DIRECTLY (t256 deleted; same f2b(y) ->
// bit-identical Ct for the projections).
// ---------------------------------------------------------------------------
__global__ __launch_bounds__(512)
void conv_mfma(const __bf16* __restrict__ Wt, const __bf16* __restrict__ Xp,
               const __bf16* __restrict__ zrow, const float* __restrict__ scA,
               const float* __restrict__ shB, const float* __restrict__ prr,
               const float* __restrict__ prd, __bf16* __restrict__ Ct)
{
    __shared__ __bf16 As[3 * 64 * 64];      // 24 KB
    __shared__ __bf16 Bs[2 * 385 * 64];     // 96.25 KB (row 384 = zeros)

    const int t = threadIdx.x;
    const int y0 = blockIdx.x * 4;
    const int m0 = blockIdx.y * 64;
    const int mb = blockIdx.z;
    const int mod = mb >> 1;

    const __bf16* Am = Wt + (long)mod * (9 * 256 * 512);
    const __bf16* Xb = Xp + (long)mb * NPIX * 512;

    const int lane = t & 63, quad = lane >> 4, l15 = lane & 15, w = t >> 6;
    const int wy = w & 3, wo = w >> 2;

    if (t < 16)
        *(f32x4*)((char*)Bs + (t >> 3) * 49280 + 49152 + (t & 7) * 16) = (f32x4)0.f;
    asm volatile("s_waitcnt lgkmcnt(0)" ::: "memory");

    auto stage_a = [&](int buf, int tap, int cc) {   // 1 load/thread (8KB)
        int r  = w * 8 + (lane >> 3);
        int sl = (lane & 7) ^ (r & 7);
        const __bf16* src = Am + (long)tap * 131072 + (long)(m0 + r) * 512
                          + cc * 64 + sl * 8;
        load_lds16(src, (char*)As + buf * 8192 + w * 1024);
    };
    auto stage_b = [&](int buf, int cc) {            // 6 loads/thread (48KB)
#pragma unroll
        for (int k = 0; k < 6; ++k) {
            int r  = w * 48 + k * 8 + (lane >> 3);
            int sl = (lane & 7) ^ (r & 7);
            int hr = r >> 6, xx = r & 63;
            int gy = y0 + hr - 1;
            const __bf16* src = ((unsigned)gy < 64u)
                ? Xb + (long)(gy * 64 + xx) * 512 + cc * 64 + sl * 8
                : zrow + sl * 8;
            load_lds16(src, (char*)Bs + buf * 49280 + (w * 48 + k * 8) * 128);
        }
    };

    f32x4 acc[2][4];
#pragma unroll
    for (int i = 0; i < 2; ++i)
#pragma unroll
        for (int j = 0; j < 4; ++j) acc[i][j] = (f32x4)0.f;

    stage_b(0, 0);
    stage_a(0, 0, 0);
    stage_a(1, 1, 0);

    const int soffA0 = ((quad ^ (l15 & 7)) << 4);
    const int soffA1 = (((4 | quad) ^ (l15 & 7)) << 4);

    for (int c = 0; c < 8; ++c) {
        for (int tp = 0; tp < 9; ++tp) {
            const int s = c * 9 + tp;
            if (s == 71)                  { asm volatile("s_waitcnt vmcnt(0)" ::: "memory"); }
            else if (tp >= 7 && c < 7)    { asm volatile("s_waitcnt vmcnt(7)" ::: "memory"); }
            else                          { asm volatile("s_waitcnt vmcnt(1)" ::: "memory"); }
            __builtin_amdgcn_sched_barrier(0);
            __builtin_amdgcn_s_barrier();
            __builtin_amdgcn_sched_barrier(0);

            if (s + 2 < 72) {
                int c2 = (tp + 2 >= 9) ? c + 1 : c;
                int t2 = (tp + 2 >= 9) ? tp - 7 : tp + 2;
                int b2 = (s + 2) % 3;
                stage_a(b2, t2, c2);
            }
            __builtin_amdgcn_sched_barrier(0);
            if (tp == 6 && c < 7) stage_b((c + 1) & 1, c + 1);
            __builtin_amdgcn_sched_barrier(0);

            const char* ab = (const char*)As + (s % 3) * 8192;
            const char* bb = (const char*)Bs + (c & 1) * 49280;
            const int dy = tp / 3 - 1, dx = tp % 3 - 1;
            const int hr = wy + 1 + dy;
            int rb[4];
#pragma unroll
            for (int fj = 0; fj < 4; ++fj) {
                int x = fj * 16 + l15 + dx;
                rb[fj] = ((unsigned)x < 64u) ? hr * 64 + x : 384;
            }
#pragma unroll
            for (int kk = 0; kk < 2; ++kk) {
                const int slq = kk * 4 + quad;
                bf16x8 af[2], bfr[4];
#pragma unroll
                for (int i = 0; i < 2; ++i)
                    af[i] = *(const bf16x8*)(ab + (wo * 32 + 16 * i + l15) * 128
                                             + (kk ? soffA1 : soffA0));
#pragma unroll
                for (int fj = 0; fj < 4; ++fj)
                    bfr[fj] = *(const bf16x8*)(bb + rb[fj] * 128
                                               + ((slq ^ (rb[fj] & 7)) << 4));
#pragma unroll
                for (int i = 0; i < 2; ++i)
#pragma unroll
                    for (int fj = 0; fj < 4; ++fj)
                        acc[i][fj] = __builtin_amdgcn_mfma_f32_16x16x32_bf16(
                            af[i], bfr[fj], acc[i][fj], 0, 0, 0);
            }
        }
    }

    // epilogue: BN + PReLU, bf16 store to Ct[pix][256] (transposed layout).
    // Per-block region = 256 pix x 64 oc = 16KB -> L2 coalesces to full lines.
    const float alpha = (mod ? prd : prr)[0];
    __bf16* ctp = Ct + (long)mb * (NPIX * 256);
    const int nbase = (y0 + wy) * 64;
#pragma unroll
    for (int i = 0; i < 2; ++i) {
#pragma unroll
        for (int r = 0; r < 4; ++r) {
            int oc = m0 + wo * 32 + 16 * i + quad * 4 + r;
            float sc = scA[mod * 256 + oc];
            float sh = shB[mod * 256 + oc];
#pragma unroll
            for (int fj = 0; fj < 4; ++fj) {
                int n = nbase + 16 * fj + l15;
                float y = acc[i][fj][r] * sc + sh;
                y = (y > 0.f) ? y : alpha * y;
                ctp[(long)n * 256 + oc] = f2b(y);
            }
        }
    }
}

// ---------------------------------------------------------------------------
// 1x1-projection MFMA GEMM. mode 0 output scaled by oscale (log2e for Q).
// ---------------------------------------------------------------------------
__global__ __launch_bounds__(256)
void proj_mfma(const __bf16* __restrict__ Wb, int mstride,
               const __bf16* __restrict__ Bt,
               const float* __restrict__ bias_r, const float* __restrict__ bias_d,
               __bf16* __restrict__ dstT, __bf16* __restrict__ dstV,
               float* __restrict__ dstU,
               const float* __restrict__ resid_r, const float* __restrict__ resid_d,
               int mode, float oscale)
{
    __shared__ __bf16 As[128 * 32];
    __shared__ __bf16 Bs[128 * 32];

    const int t = threadIdx.x;
    const int n0 = blockIdx.x * 128;
    const int m0 = blockIdx.y * 128;
    const int mb = blockIdx.z;
    const int mod = mb >> 1, b = mb & 1;

    const __bf16* Am = Wb + (long)mod * mstride;
    const __bf16* Bm = Bt + (long)mb * (NPIX * 256);
    const float* bias = mod ? bias_d : bias_r;

    const int rowa = t >> 2, c16 = t & 3;
    char* ldsA0 = (char*)As + (t >> 6) * 1024;
    char* ldsA1 = ldsA0 + 4096;
    char* ldsB0 = (char*)Bs + (t >> 6) * 1024;
    char* ldsB1 = ldsB0 + 4096;
    const __bf16* srcA = Am + (long)(m0 + rowa) * 256 + c16 * 8;
    const __bf16* srcB = Bm + (long)(n0 + rowa) * 256 + c16 * 8;

    const int lane = t & 63, quad = lane >> 4, l15 = lane & 15, w = t >> 6;
    const int mw = (w >> 1) * 64, nw = (w & 1) * 64;
    const char* abase = (const char*)As + (mw + l15) * 64 + quad * 16;
    const char* bbase = (const char*)Bs + (nw + l15) * 64 + quad * 16;

    f32x4 acc[4][4];
#pragma unroll
    for (int i = 0; i < 4; ++i)
#pragma unroll
        for (int j = 0; j < 4; ++j) acc[i][j] = (f32x4)0.f;

    for (int kc = 0; kc < 256; kc += 32) {
        load_lds16(srcA + kc, ldsA0);
        load_lds16(srcA + kc + 16384, ldsA1);
        load_lds16(srcB + kc, ldsB0);
        load_lds16(srcB + kc + 16384, ldsB1);
        __syncthreads();

        bf16x8 af[4], bfr[4];
#pragma unroll
        for (int i = 0; i < 4; ++i) af[i]  = *(const bf16x8*)(abase + i * 1024);
#pragma unroll
        for (int j = 0; j < 4; ++j) bfr[j] = *(const bf16x8*)(bbase + j * 1024);
#pragma unroll
        for (int i = 0; i < 4; ++i)
#pragma unroll
            for (int j = 0; j < 4; ++j)
                acc[i][j] = __builtin_amdgcn_mfma_f32_16x16x32_bf16(
                    af[i], bfr[j], acc[i][j], 0, 0, 0);
        __syncthreads();
    }

    if (mode == 0) {
        if (mw == 0) {
            __bf16* dbase = dstT + (long)mb * (NPIX * 32);
#pragma unroll
            for (int fi = 0; fi < 2; ++fi)
#pragma unroll
                for (int r = 0; r < 4; ++r) {
                    int oc = 16 * fi + quad * 4 + r;
                    float bi = bias[oc];
#pragma unroll
                    for (int fj = 0; fj < 4; ++fj) {
                        int n = n0 + nw + 16 * fj + l15;
                        dbase[(long)n * 32 + oc] = f2b((acc[fi][fj][r] + bi) * oscale);
                    }
                }
        }
    } else if (mode == 1) {
        __bf16* dv = dstV + (long)mb * (256 * NPIX);
#pragma unroll
        for (int fi = 0; fi < 4; ++fi)
#pragma unroll
            for (int r = 0; r < 4; ++r) {
                int c = m0 + mw + 16 * fi + quad * 4 + r;
                float bi = bias[c];
                __bf16* row = dv + (long)c * NPIX;
#pragma unroll
                for (int fj = 0; fj < 4; ++fj) {
                    int n = n0 + nw + 16 * fj + l15;
                    row[n] = f2b(acc[fi][fj][r] + bi);
                }
            }
    } else {
        float* du = dstU + (long)mod * 4194304 + (long)b * 2097152;
        const float* rs = (mod ? resid_d : resid_r) + (long)b * 2097152;
#pragma unroll
        for (int fi = 0; fi < 4; ++fi)
#pragma unroll
            for (int r = 0; r < 4; ++r) {
                int oc = m0 + mw + 16 * fi + quad * 4 + r;
                float bi = bias[oc];
                const float* rrow = rs + (long)oc * NPIX;
                float* orow = du + (long)oc * NPIX;
#pragma unroll
                for (int fj = 0; fj < 4; ++fj) {
                    int n = n0 + nw + 16 * fj + l15;
                    orow[n] = acc[fi][fj][r] + bi + rrow[n];
                }
            }
    }
}

// ---------------------------------------------------------------------------
// MAX-ONLY MFMA row stats over a j-SEGMENT [seg*1024, +1024): partial m.
// grid (32 i, 4 mbo, 4 seg) = 512 blocks. Unchanged from round 16.
// ---------------------------------------------------------------------------
__global__ __launch_bounds__(256)
void attn_stats_mfma(const __bf16* __restrict__ Qt, const __bf16* __restrict__ Kt,
                     float* __restrict__ rmp)
{
    __shared__ __bf16 Qs[128 * 32];
    __shared__ __bf16 Ks[128 * 32];
    __shared__ float redm[2][128];

    const int t  = threadIdx.x;
    const int i0 = blockIdx.x * 128;
    const int mbo = blockIdx.y;
    const int o  = mbo >> 1, b = mbo & 1;
    const int seg = blockIdx.z;
    const int jbase = seg * 1024;
    const int mbK = o * 2 + b, mbQ = (1 - o) * 2 + b;

    const __bf16* Qg = Qt + (long)mbQ * 131072;
    const __bf16* Kg = Kt + (long)mbK * 131072;

    const int lane = t & 63, quad = lane >> 4, l15 = lane & 15, w = t >> 6;
    const int mS = (w >> 1) * 64;
    const int nS = (w & 1) * 64;

    const int drow = w * 16 + (lane >> 2);                  // staging dest row
    const int ssl  = ((lane & 3) ^ ((lane >> 3) & 3)) * 16; // swizzled src slot
    const int rsl  = (quad ^ ((l15 >> 1) & 3)) << 4;        // swizzled read slot

    load_lds16((const char*)Qg + (long)(i0 + drow) * 64 + ssl, (char*)Qs + w * 1024);
    load_lds16((const char*)Qg + (long)(i0 + 64 + drow) * 64 + ssl,
               (char*)Qs + 4096 + w * 1024);
    __syncthreads();

    bf16x8 qa[4];
#pragma unroll
    for (int fi = 0; fi < 4; ++fi)
        qa[fi] = *(const bf16x8*)((const char*)Qs + (mS + 16 * fi + l15) * 64 + rsl);

    const f32x4 zero4 = (f32x4)0.f;
    float m_t[16];
#pragma unroll
    for (int e = 0; e < 16; ++e) m_t[e] = -3.0e38f;

    for (int j0 = jbase; j0 < jbase + 1024; j0 += 128) {
        __syncthreads();
        load_lds16((const char*)Kg + (long)(j0 + drow) * 64 + ssl, (char*)Ks + w * 1024);
        load_lds16((const char*)Kg + (long)(j0 + 64 + drow) * 64 + ssl,
                   (char*)Ks + 4096 + w * 1024);
        __syncthreads();

        bf16x8 kb[4];
#pragma unroll
        for (int fj = 0; fj < 4; ++fj)
            kb[fj] = *(const bf16x8*)((const char*)Ks + (nS + 16 * fj + l15) * 64 + rsl);
#pragma unroll
        for (int fi = 0; fi < 4; ++fi) {
            f32x4 sf[4];
#pragma unroll
            for (int fj = 0; fj < 4; ++fj)
                sf[fj] = __builtin_amdgcn_mfma_f32_16x16x32_bf16(qa[fi], kb[fj], zero4, 0, 0, 0);
#pragma unroll
            for (int r = 0; r < 4; ++r) {
                int e = fi * 4 + r;
                float a = fmaxf(fmaxf(sf[0][r], sf[1][r]), fmaxf(sf[2][r], sf[3][r]));
                m_t[e] = fmaxf(m_t[e], a);
            }
        }
    }

#pragma unroll
    for (int d = 1; d < 16; d <<= 1)
#pragma unroll
        for (int e = 0; e < 16; ++e)
            m_t[e] = fmaxf(m_t[e], __shfl_xor(m_t[e], d, 64));
    if (l15 == 0) {
#pragma unroll
        for (int fi = 0; fi < 4; ++fi)
#pragma unroll
            for (int r = 0; r < 4; ++r)
                redm[w & 1][mS + 16 * fi + quad * 4 + r] = m_t[fi * 4 + r];
    }
    __syncthreads();
    if (t < 128)
        rmp[seg * 16384 + mbo * 4096 + i0 + t] = fmaxf(redm[0][t], redm[1][t]);
}

// ---------------------------------------------------------------------------
// Merge 4-segment maxes: rmb = max_s rmp[s]. grid 64 x 256.
// ---------------------------------------------------------------------------
__global__ __launch_bounds__(256)
void stats_merge(const float* __restrict__ rmp, float* __restrict__ rmb)
{
    int idx = blockIdx.x * 256 + threadIdx.x;
    float m = rmp[idx];
#pragma unroll
    for (int s = 1; s < 4; ++s) m = fmaxf(m, rmp[s * 16384 + idx]);
    rmb[idx] = m;
}

// ---------------------------------------------------------------------------
// Fused MFMA PV v7: byte-exact v4 staging + P phase (3 barriers, 2 blocks/CU,
// XCD grouping, conflict-free swizzles). l accumulated in the PV phase:
// wave w sums its own pb[w] fragments (rows 16w+l15; 16 bf16 cvt+add/step
// co-issued under the 64-MFMA cluster); quad butterfly at the end.
// ---------------------------------------------------------------------------
__global__ __launch_bounds__(256, 2)
void attn_pv_mfma(const __bf16* __restrict__ Qt, const __bf16* __restrict__ Kt,
                  const __bf16* __restrict__ Vb,
                  float* __restrict__ part0, float* __restrict__ part1,
                  const float* __restrict__ rmb, float* __restrict__ lbuf)
{
    __shared__ __bf16 Qs[64 * 32];        // 4KB  [64 i][32ch]
    __shared__ __bf16 Ks[64 * 32];        // 4KB  [64 j][32ch]
    __shared__ __bf16 Vs[2 * 256 * 32];   // 32KB [2ks][256c][32j]
    __shared__ __bf16 Ps[64 * 64];        // 8KB  [64 i][64 j] swizzled

    const int t  = threadIdx.x;
    const int bx = blockIdx.x;
    const int grp = bx & 7;               // XCD group = (mb<<1)|seg
    const int i0  = (bx >> 3) * 64;
    const int seg = grp & 1;
    const int mb  = grp >> 1;
    const int o  = mb >> 1, b = mb & 1;
    const int mbQ = (1 - o) * 2 + b;
    const int jbase = seg * 2048;

    const __bf16* Qg = Qt + (long)mbQ * 131072;
    const __bf16* Kg = Kt + (long)mb * 131072;
    const __bf16* Vg = Vb + (long)mb * 1048576;
    const float* rm = rmb + mb * 4096;

    const int lane = t & 63, quad = lane >> 4, l15 = lane & 15, w = t >> 6;
    const int iS = w * 16;                // this wave's S row block
    const int cw = w * 64;                // this wave's PV c block

    const int drow = w * 16 + (lane >> 2);                  // staging dest row
    const int ssl  = ((lane & 3) ^ ((lane >> 3) & 3)) * 16; // swizzled src slot
    const int rsl  = (quad ^ ((l15 >> 1) & 3)) << 4;        // swizzled read slot

    // Q stage (64 rows, 4KB)
    load_lds16((const char*)Qg + (long)(i0 + drow) * 64 + ssl, (char*)Qs + w * 1024);

    float mlv[4];
#pragma unroll
    for (int r = 0; r < 4; ++r) mlv[r] = rm[i0 + iS + quad * 4 + r];
    float lsum = 0.f;                     // row i0+16w+l15, this quad's cols

    f32x4 acc[4][4];
#pragma unroll
    for (int i = 0; i < 4; ++i)
#pragma unroll
        for (int j = 0; j < 4; ++j) acc[i][j] = (f32x4)0.f;
    const f32x4 zero4 = (f32x4)0.f;

    __syncthreads();
    const bf16x8 qa = *(const bf16x8*)((const char*)Qs + (iS + l15) * 64 + rsl);

    for (int j0 = jbase; j0 < jbase + 2048; j0 += 64) {
        __syncthreads();                    // prev-step consumers done
        load_lds16((const char*)Kg + (long)(j0 + drow) * 64 + ssl,
                   (char*)Ks + w * 1024);
        __syncthreads();                    // K ready (only K in flight)

        // issue V loads now; latency hides under S + P (drained at next barrier)
#pragma unroll
        for (int ii = 0; ii < 8; ++ii) {
            int ks = ii >> 2;
            int c  = (ii & 3) * 64 + drow;
            load_lds16((const char*)Vg + (long)c * 8192 + (long)(j0 + ks * 32) * 2 + ssl,
                       (char*)Vs + ii * 4096 + w * 1024);
        }

        // S = Q K^T for rows [iS,iS+16), cols [0,64)
        f32x4 sA[4];
#pragma unroll
        for (int fj = 0; fj < 4; ++fj) {
            bf16x8 kb = *(const bf16x8*)((const char*)Ks + (16 * fj + l15) * 64 + rsl);
            sA[fj] = __builtin_amdgcn_mfma_f32_16x16x32_bf16(qa, kb, zero4, 0, 0, 0);
        }
        // P = exp2(S - m) -> swizzled Ps (byte-exact v4: no extra work here)
#pragma unroll
        for (int fj = 0; fj < 4; ++fj)
#pragma unroll
            for (int r = 0; r < 4; ++r) {
                int il = iS + quad * 4 + r;
                int boff = (il * 128 + (16 * fj + l15) * 2) ^ ((il & 7) << 4);
                *(__bf16*)((char*)Ps + boff) = f2b(exp2f(sA[fj][r] - mlv[r]));
            }
        __syncthreads();                    // P visible, V staged

#pragma unroll
        for (int ks = 0; ks < 2; ++ks) {
            bf16x8 va[4], pb[4];
#pragma unroll
            for (int fi = 0; fi < 4; ++fi)
                va[fi] = *(const bf16x8*)((const char*)Vs + ks * 16384 +
                                          (cw + 16 * fi + l15) * 64 + rsl);
#pragma unroll
            for (int fj = 0; fj < 4; ++fj) {
                int ip = 16 * fj + l15;
                int boff = (ip * 128 + ks * 64 + quad * 16) ^ ((ip & 7) << 4);
                pb[fj] = *(const bf16x8*)((const char*)Ps + boff);
            }
            // l accumulation from this wave's own row fragment (fj == w):
            // row 16w+l15, cols ks*32+quad*8+e — co-issues under the MFMAs.
            {
                bf16x8 pw = pb[w];
#pragma unroll
                for (int e = 0; e < 8; ++e) lsum += (float)pw[e];
            }
#pragma unroll
            for (int fi = 0; fi < 4; ++fi)
#pragma unroll
                for (int fj = 0; fj < 4; ++fj)
                    acc[fi][fj] = __builtin_amdgcn_mfma_f32_16x16x32_bf16(
                        va[fi], pb[fj], acc[fi][fj], 0, 0, 0);
        }
    }

    // raw partial store (merge/normalize in zred)
    float* pg = (seg ? part1 : part0) + (long)mb * 1048576;
#pragma unroll
    for (int fi = 0; fi < 4; ++fi) {
#pragma unroll
        for (int r = 0; r < 4; ++r) {
            int c = cw + 16 * fi + quad * 4 + r;
            float* zr = pg + (long)c * 4096;
#pragma unroll
            for (int fj = 0; fj < 4; ++fj)
                zr[i0 + 16 * fj + l15] = acc[fi][fj][r];
        }
    }

    // l: combine the 4 quads' disjoint col-partials of row i0+16w+l15
    lsum += __shfl_xor(lsum, 16, 64);
    lsum += __shfl_xor(lsum, 32, 64);
    if (quad == 0)
        lbuf[seg * 16384 + mb * 4096 + i0 + 16 * w + l15] = lsum;
}

// ---------------------------------------------------------------------------
// z = (gamma/(l0+l1))*(part0+part1) + conv(Ct bf16), transposed bf16 store.
// grid (128, 8, 4). Conv residual added POST-transpose from Ct[pix][256].
// ---------------------------------------------------------------------------
__global__ __launch_bounds__(256)
void zred_t(const float* __restrict__ p0, const float* __restrict__ p1,
            const __bf16* __restrict__ Ct, __bf16* __restrict__ Zt,
            const float* __restrict__ g_r, const float* __restrict__ g_d,
            const float* __restrict__ lbuf)
{
    __shared__ float tile[32][33];
    const int t = threadIdx.x;
    const int pix0 = blockIdx.x * 32;
    const int c0 = blockIdx.y * 32;
    const int mb = blockIdx.z;
    const int o = mb >> 1;
    const float gamma = (o ? g_d : g_r)[0];
    const long base = (long)mb * 1048576;

    int i = t >> 3, j4 = (t & 7) * 4;
    const float* l0p = lbuf + mb * 4096;
    const float* l1p = lbuf + 16384 + mb * 4096;
    float4 la = *(const float4*)&l0p[pix0 + j4];
    float4 lc = *(const float4*)&l1p[pix0 + j4];
    float g0 = gamma / (la.x + lc.x);
    float g1 = gamma / (la.y + lc.y);
    float g2 = gamma / (la.z + lc.z);
    float g3 = gamma / (la.w + lc.w);

    long row = base + (long)(c0 + i) * 4096 + pix0 + j4;
    float4 a = *(const float4*)&p0[row];
    float4 b = *(const float4*)&p1[row];
    tile[i][j4 + 0] = g0 * (a.x + b.x);
    tile[i][j4 + 1] = g1 * (a.y + b.y);
    tile[i][j4 + 2] = g2 * (a.z + b.z);
    tile[i][j4 + 3] = g3 * (a.w + b.w);
    __syncthreads();
    int j = t >> 3, i4 = (t & 7) * 4;
    bf16x4 cv = *(const bf16x4*)&Ct[(long)mb * NPIX * 256 +
                                    (long)(pix0 + j) * 256 + c0 + i4];
    bf16x4 oq;
    oq.x = f2b(tile[i4 + 0][j] + (float)cv.x);
    oq.y = f2b(tile[i4 + 1][j] + (float)cv.y);
    oq.z = f2b(tile[i4 + 2][j] + (float)cv.z);
    oq.w = f2b(tile[i4 + 3][j] + (float)cv.w);
    *(bf16x4*)&Zt[(long)mb * NPIX * 256 + (long)(pix0 + j) * 256 + c0 + i4] = oq;
}

// ---------------------------------------------------------------------------
// Host launcher
// ---------------------------------------------------------------------------
// ws layout (float slots) — as round 16; the fp32 `conv` slot is now DEAD
// (conv writes Ct directly; t256 deleted). rmp scratch still lives in part0.
extern "C" void kernel_launch(void* const* d_in, const int* in_sizes, int n_in,
                              void* d_out, int out_size, void* d_ws, size_t ws_size,
                              hipStream_t stream)
{
    const float* in_rgb = (const float*)d_in[0];
    const float* in_dsm = (const float*)d_in[1];
    auto P = [&](int i) { return (const float*)d_in[i]; };

    float* ws    = (float*)d_ws;
    float* part0 = ws + 4194304;
    float* rmb   = ws + 8388608;
    float* lbuf  = ws + 8421376;
    float* rmp   = part0;            // [4seg][4][4096] scratch, dead before pv
    float* scA   = ws + 8486912;
    float* shB   = ws + 8487424;
    __bf16* zrow = (__bf16*)(ws + 8487936);
    __bf16* Wt   = (__bf16*)(ws + 8488192);
    __bf16* Xp   = (__bf16*)(ws + 9667840);
    float*  part1 = ws + 9667840;            // aliases Xp (dead after conv)
    __bf16* Qt   = (__bf16*)(ws + 13862144);
    __bf16* Kt   = (__bf16*)(ws + 14124288);
    __bf16* Vbb  = (__bf16*)(ws + 14386432);
    __bf16* Ct   = (__bf16*)(ws + 16483584);
    __bf16* Zt   = (__bf16*)(ws + 18580736);
    __bf16* Wq   = (__bf16*)(ws + 20677888);
    __bf16* Wk   = (__bf16*)(ws + 20710656);
    __bf16* Wv   = (__bf16*)(ws + 20743424);
    __bf16* Wu   = (__bf16*)(ws + 20808960);

    // prep
    prep_w<<<2307, 256, 0, stream>>>(
        P(2), P(18), P(3), P(4), P(5), P(6), P(7),
        P(19), P(20), P(21), P(22), P(23),
        Wt, scA, shB, zrow);
    prep_gw<<<512, 256, 0, stream>>>(
        P(9), P(25), P(11), P(27), P(13), P(29), P(15), P(31),
        Wq, Wk, Wv, Wu);
    xpose<<<dim3(128, 16, 4), 256, 0, stream>>>(in_rgb, in_dsm, Xp);

    // conv3x3 + BN + PReLU -> Ct bf16 [pix][256] directly (t256 deleted)
    conv_mfma<<<dim3(16, 4, 4), 512, 0, stream>>>(
        Wt, Xp, zrow, scA, shB, P(8), P(24), Ct);

    // q/k/v projections (Q pre-scaled by log2e -> exp2 softmax domain)
    proj_mfma<<<dim3(32, 1, 4), 256, 0, stream>>>(
        Wq, 32768, Ct, P(10), P(26), Qt, nullptr, nullptr, nullptr, nullptr,
        0, 1.4426950408889634f);
    proj_mfma<<<dim3(32, 1, 4), 256, 0, stream>>>(
        Wk, 32768, Ct, P(12), P(28), Kt, nullptr, nullptr, nullptr, nullptr,
        0, 1.0f);
    proj_mfma<<<dim3(32, 2, 4), 256, 0, stream>>>(
        Wv, 65536, Ct, P(14), P(30), nullptr, Vbb, nullptr, nullptr, nullptr,
        1, 1.0f);

    // max-only stats (j-split x4, 512 blocks) + max merge
    attn_stats_mfma<<<dim3(32, 4, 4), 256, 0, stream>>>(Qt, Kt, rmp);
    stats_merge<<<64, 256, 0, stream>>>(rmp, rmb);

    // fused PV v7 (v4 staging; l from pb fragments in the PV phase)
    attn_pv_mfma<<<512, 256, 0, stream>>>(
        Qt, Kt, Vbb, part0, part1, rmb, lbuf);

    // z = (gamma/(l0+l1))*(p0+p1) + Ct, transpose + bf16 -> Zt
    zred_t<<<dim3(128, 8, 4), 256, 0, stream>>>(
        part0, part1, Ct, Zt, P(17), P(33), lbuf);

    // up projection + input residual -> fp32 out
    proj_mfma<<<dim3(32, 4, 4), 256, 0, stream>>>(
        Wu, 131072, Zt, P(16), P(32), nullptr, nullptr, (float*)d_out,
        in_rgb, in_dsm, 2, 1.0f);
}

// Round 11
// 330.744 us; speedup vs baseline: 1.2241x; 1.2241x over previous
//
#include <hip/hip_runtime.h>
#include <hip/hip_bf16.h>
#include <stdint.h>

// fp32 I/O. Conv3x3, 1x1 projections, and attention run as bf16 MFMA.
// Round 16: max-only stats + l-in-P-phase + zred merge -> 333us (pv 67.1).
// Round 17: two bundled changes: (a) l moved to PV phase via pb[w] — runtime
//   ext_vector index (rule #20) -> compiler emitted 4-way cndmask selects on
//   the PV critical path, pv 67->150us, REVERTED; (b) t256 deleted + conv
//   writes Ct bf16 directly + zred residual from Ct — measured ~11us WIN
//   (non-pv 265.9 -> 255.0), KEPT.
// Round 18 (this): clean recombination — r16's pv byte-exact (l in P phase,
//   f32 p values) + r17's conv/zred path. No new experiments.

constexpr int CINCH = 512;
constexpr int NPIX  = 4096;   // 64*64

typedef __bf16 bf16x8 __attribute__((ext_vector_type(8)));
typedef __bf16 bf16x4 __attribute__((ext_vector_type(4)));
typedef float  f32x4  __attribute__((ext_vector_type(4)));

__device__ __forceinline__ __bf16 f2b(float f) {
    __hip_bfloat16 h = __float2bfloat16(f);
    return *reinterpret_cast<__bf16*>(&h);
}

__device__ __forceinline__ void load_lds16(const void* g, void* l) {
    __builtin_amdgcn_global_load_lds(
        (const __attribute__((address_space(1))) unsigned int*)(uintptr_t)g,
        (__attribute__((address_space(3))) unsigned int*)(uintptr_t)l,
        16, 0, 0);
}

// ---------------------------------------------------------------------------
// Prep A: conv weights fp32 [oc][ic][9] -> Wt bf16 [mod][tap][oc][ic];
// BN scale/shift tables; zero row. grid 2307 x 256.
// ---------------------------------------------------------------------------
__global__ __launch_bounds__(256)
void prep_w(const float* __restrict__ w_r, const float* __restrict__ w_d,
            const float* __restrict__ cb_r, const float* __restrict__ bg_r,
            const float* __restrict__ bb_r, const float* __restrict__ bm_r,
            const float* __restrict__ bv_r,
            const float* __restrict__ cb_d, const float* __restrict__ bg_d,
            const float* __restrict__ bb_d, const float* __restrict__ bm_d,
            const float* __restrict__ bv_d,
            __bf16* __restrict__ Wt, float* __restrict__ scA,
            float* __restrict__ shB, __bf16* __restrict__ zrow)
{
    const int t = threadIdx.x;
    const int blk = blockIdx.x;
    if (blk < 2304) {
        int gid = blk * 1024 + t * 4;
        int mod = gid >= 1179648;
        int o2  = gid - mod * 1179648;
        int tap = o2 >> 17;
        int r   = o2 & 131071;
        int oc  = r >> 9;
        int ic  = r & 511;
        const float* wsrc = mod ? w_d : w_r;
        long base = ((long)(oc * 512 + ic)) * 9 + tap;
        bf16x4 v;
        v.x = f2b(wsrc[base]);
        v.y = f2b(wsrc[base + 9]);
        v.z = f2b(wsrc[base + 18]);
        v.w = f2b(wsrc[base + 27]);
        *(bf16x4*)&Wt[gid] = v;
    } else if (blk == 2304) {
        unsigned short* z = (unsigned short*)zrow;
        z[t] = 0; z[t + 256] = 0;
    } else {
        int mod = blk - 2305;
        const float* cb = mod ? cb_d : cb_r;
        const float* bg = mod ? bg_d : bg_r;
        const float* bb = mod ? bb_d : bb_r;
        const float* bm = mod ? bm_d : bm_r;
        const float* bv = mod ? bv_d : bv_r;
        int oc = t;
        float sc = bg[oc] * rsqrtf(bv[oc] + 1e-5f);
        scA[mod * 256 + oc] = sc;
        shB[mod * 256 + oc] = (cb[oc] - bm[oc]) * sc + bb[oc];
    }
}

// ---------------------------------------------------------------------------
// Prep B: projection weights fp32 -> bf16. Wq/Wk padded to 128 rows (zeros).
// ---------------------------------------------------------------------------
__global__ __launch_bounds__(256)
void prep_gw(const float* __restrict__ qw_r, const float* __restrict__ qw_d,
             const float* __restrict__ kw_r, const float* __restrict__ kw_d,
             const float* __restrict__ vw_r, const float* __restrict__ vw_d,
             const float* __restrict__ uw_r, const float* __restrict__ uw_d,
             __bf16* __restrict__ Wq, __bf16* __restrict__ Wk,
             __bf16* __restrict__ Wv, __bf16* __restrict__ Wu)
{
    int gid = blockIdx.x * 1024 + threadIdx.x * 4;
    __bf16* dst;
    float4 f = make_float4(0.f, 0.f, 0.f, 0.f);
    if (gid < 65536) {
        int mod = gid >> 15, e = gid & 32767;
        dst = Wq + gid;
        if (e < 8192) f = *(const float4*)((mod ? qw_d : qw_r) + e);
    } else if (gid < 131072) {
        int g = gid - 65536;
        int mod = g >> 15, e = g & 32767;
        dst = Wk + g;
        if (e < 8192) f = *(const float4*)((mod ? kw_d : kw_r) + e);
    } else if (gid < 262144) {
        int g = gid - 131072;
        int mod = g >> 16, e = g & 65535;
        dst = Wv + g;
        f = *(const float4*)((mod ? vw_d : vw_r) + e);
    } else {
        int g = gid - 262144;
        int mod = g >> 17, e = g & 131071;
        dst = Wu + g;
        f = *(const float4*)((mod ? uw_d : uw_r) + e);
    }
    bf16x4 o; o.x = f2b(f.x); o.y = f2b(f.y); o.z = f2b(f.z); o.w = f2b(f.w);
    *(bf16x4*)dst = o;
}

// ---------------------------------------------------------------------------
// Prep C: X fp32 [mod][b][512][4096] -> Xp bf16 [modb][4096pix][512ic]
// ---------------------------------------------------------------------------
__global__ __launch_bounds__(256)
void xpose(const float* __restrict__ inr, const float* __restrict__ ind,
           __bf16* __restrict__ Xp)
{
    __shared__ float tile[32][33];
    const int t = threadIdx.x;
    const int p0 = blockIdx.x * 32;
    const int ic0 = blockIdx.y * 32;
    const int mb = blockIdx.z;
    const int mod = mb >> 1, b = mb & 1;
    const float* src = (mod ? ind : inr) + (long)b * CINCH * NPIX;

    int i = t >> 3, j4 = (t & 7) * 4;
    float4 v = *(const float4*)&src[(long)(ic0 + i) * NPIX + p0 + j4];
    tile[i][j4 + 0] = v.x; tile[i][j4 + 1] = v.y;
    tile[i][j4 + 2] = v.z; tile[i][j4 + 3] = v.w;
    __syncthreads();
    int j = t >> 3, i4 = (t & 7) * 4;
    bf16x4 o;
    o.x = f2b(tile[i4 + 0][j]);
    o.y = f2b(tile[i4 + 1][j]);
    o.z = f2b(tile[i4 + 2][j]);
    o.w = f2b(tile[i4 + 3][j]);
    *(bf16x4*)&Xp[((long)mb * NPIX + p0 + j) * 512 + ic0 + i4] = o;
}

// ---------------------------------------------------------------------------
// Conv3x3 implicit-GEMM MFMA v5 (halo, 8 waves). Epilogue writes Ct bf16
// [pix][256] directly (t256 deleted; same f2b(y) -> bit-identical Ct).
// ---------------------------------------------------------------------------
__global__ __launch_bounds__(512)
void conv_mfma(const __bf16* __restrict__ Wt, const __bf16* __restrict__ Xp,
               const __bf16* __restrict__ zrow, const float* __restrict__ scA,
               const float* __restrict__ shB, const float* __restrict__ prr,
               const float* __restrict__ prd, __bf16* __restrict__ Ct)
{
    __shared__ __bf16 As[3 * 64 * 64];      // 24 KB
    __shared__ __bf16 Bs[2 * 385 * 64];     // 96.25 KB (row 384 = zeros)

    const int t = threadIdx.x;
    const int y0 = blockIdx.x * 4;
    const int m0 = blockIdx.y * 64;
    const int mb = blockIdx.z;
    const int mod = mb >> 1;

    const __bf16* Am = Wt + (long)mod * (9 * 256 * 512);
    const __bf16* Xb = Xp + (long)mb * NPIX * 512;

    const int lane = t & 63, quad = lane >> 4, l15 = lane & 15, w = t >> 6;
    const int wy = w & 3, wo = w >> 2;

    if (t < 16)
        *(f32x4*)((char*)Bs + (t >> 3) * 49280 + 49152 + (t & 7) * 16) = (f32x4)0.f;
    asm volatile("s_waitcnt lgkmcnt(0)" ::: "memory");

    auto stage_a = [&](int buf, int tap, int cc) {   // 1 load/thread (8KB)
        int r  = w * 8 + (lane >> 3);
        int sl = (lane & 7) ^ (r & 7);
        const __bf16* src = Am + (long)tap * 131072 + (long)(m0 + r) * 512
                          + cc * 64 + sl * 8;
        load_lds16(src, (char*)As + buf * 8192 + w * 1024);
    };
    auto stage_b = [&](int buf, int cc) {            // 6 loads/thread (48KB)
#pragma unroll
        for (int k = 0; k < 6; ++k) {
            int r  = w * 48 + k * 8 + (lane >> 3);
            int sl = (lane & 7) ^ (r & 7);
            int hr = r >> 6, xx = r & 63;
            int gy = y0 + hr - 1;
            const __bf16* src = ((unsigned)gy < 64u)
                ? Xb + (long)(gy * 64 + xx) * 512 + cc * 64 + sl * 8
                : zrow + sl * 8;
            load_lds16(src, (char*)Bs + buf * 49280 + (w * 48 + k * 8) * 128);
        }
    };

    f32x4 acc[2][4];
#pragma unroll
    for (int i = 0; i < 2; ++i)
#pragma unroll
        for (int j = 0; j < 4; ++j) acc[i][j] = (f32x4)0.f;

    stage_b(0, 0);
    stage_a(0, 0, 0);
    stage_a(1, 1, 0);

    const int soffA0 = ((quad ^ (l15 & 7)) << 4);
    const int soffA1 = (((4 | quad) ^ (l15 & 7)) << 4);

    for (int c = 0; c < 8; ++c) {
        for (int tp = 0; tp < 9; ++tp) {
            const int s = c * 9 + tp;
            if (s == 71)                  { asm volatile("s_waitcnt vmcnt(0)" ::: "memory"); }
            else if (tp >= 7 && c < 7)    { asm volatile("s_waitcnt vmcnt(7)" ::: "memory"); }
            else                          { asm volatile("s_waitcnt vmcnt(1)" ::: "memory"); }
            __builtin_amdgcn_sched_barrier(0);
            __builtin_amdgcn_s_barrier();
            __builtin_amdgcn_sched_barrier(0);

            if (s + 2 < 72) {
                int c2 = (tp + 2 >= 9) ? c + 1 : c;
                int t2 = (tp + 2 >= 9) ? tp - 7 : tp + 2;
                int b2 = (s + 2) % 3;
                stage_a(b2, t2, c2);
            }
            __builtin_amdgcn_sched_barrier(0);
            if (tp == 6 && c < 7) stage_b((c + 1) & 1, c + 1);
            __builtin_amdgcn_sched_barrier(0);

            const char* ab = (const char*)As + (s % 3) * 8192;
            const char* bb = (const char*)Bs + (c & 1) * 49280;
            const int dy = tp / 3 - 1, dx = tp % 3 - 1;
            const int hr = wy + 1 + dy;
            int rb[4];
#pragma unroll
            for (int fj = 0; fj < 4; ++fj) {
                int x = fj * 16 + l15 + dx;
                rb[fj] = ((unsigned)x < 64u) ? hr * 64 + x : 384;
            }
#pragma unroll
            for (int kk = 0; kk < 2; ++kk) {
                const int slq = kk * 4 + quad;
                bf16x8 af[2], bfr[4];
#pragma unroll
                for (int i = 0; i < 2; ++i)
                    af[i] = *(const bf16x8*)(ab + (wo * 32 + 16 * i + l15) * 128
                                             + (kk ? soffA1 : soffA0));
#pragma unroll
                for (int fj = 0; fj < 4; ++fj)
                    bfr[fj] = *(const bf16x8*)(bb + rb[fj] * 128
                                               + ((slq ^ (rb[fj] & 7)) << 4));
#pragma unroll
                for (int i = 0; i < 2; ++i)
#pragma unroll
                    for (int fj = 0; fj < 4; ++fj)
                        acc[i][fj] = __builtin_amdgcn_mfma_f32_16x16x32_bf16(
                            af[i], bfr[fj], acc[i][fj], 0, 0, 0);
            }
        }
    }

    // epilogue: BN + PReLU, bf16 store to Ct[pix][256] (transposed layout).
    const float alpha = (mod ? prd : prr)[0];
    __bf16* ctp = Ct + (long)mb * (NPIX * 256);
    const int nbase = (y0 + wy) * 64;
#pragma unroll
    for (int i = 0; i < 2; ++i) {
#pragma unroll
        for (int r = 0; r < 4; ++r) {
            int oc = m0 + wo * 32 + 16 * i + quad * 4 + r;
            float sc = scA[mod * 256 + oc];
            float sh = shB[mod * 256 + oc];
#pragma unroll
            for (int fj = 0; fj < 4; ++fj) {
                int n = nbase + 16 * fj + l15;
                float y = acc[i][fj][r] * sc + sh;
                y = (y > 0.f) ? y : alpha * y;
                ctp[(long)n * 256 + oc] = f2b(y);
            }
        }
    }
}

// ---------------------------------------------------------------------------
// 1x1-projection MFMA GEMM. mode 0 output scaled by oscale (log2e for Q).
// ---------------------------------------------------------------------------
__global__ __launch_bounds__(256)
void proj_mfma(const __bf16* __restrict__ Wb, int mstride,
               const __bf16* __restrict__ Bt,
               const float* __restrict__ bias_r, const float* __restrict__ bias_d,
               __bf16* __restrict__ dstT, __bf16* __restrict__ dstV,
               float* __restrict__ dstU,
               const float* __restrict__ resid_r, const float* __restrict__ resid_d,
               int mode, float oscale)
{
    __shared__ __bf16 As[128 * 32];
    __shared__ __bf16 Bs[128 * 32];

    const int t = threadIdx.x;
    const int n0 = blockIdx.x * 128;
    const int m0 = blockIdx.y * 128;
    const int mb = blockIdx.z;
    const int mod = mb >> 1, b = mb & 1;

    const __bf16* Am = Wb + (long)mod * mstride;
    const __bf16* Bm = Bt + (long)mb * (NPIX * 256);
    const float* bias = mod ? bias_d : bias_r;

    const int rowa = t >> 2, c16 = t & 3;
    char* ldsA0 = (char*)As + (t >> 6) * 1024;
    char* ldsA1 = ldsA0 + 4096;
    char* ldsB0 = (char*)Bs + (t >> 6) * 1024;
    char* ldsB1 = ldsB0 + 4096;
    const __bf16* srcA = Am + (long)(m0 + rowa) * 256 + c16 * 8;
    const __bf16* srcB = Bm + (long)(n0 + rowa) * 256 + c16 * 8;

    const int lane = t & 63, quad = lane >> 4, l15 = lane & 15, w = t >> 6;
    const int mw = (w >> 1) * 64, nw = (w & 1) * 64;
    const char* abase = (const char*)As + (mw + l15) * 64 + quad * 16;
    const char* bbase = (const char*)Bs + (nw + l15) * 64 + quad * 16;

    f32x4 acc[4][4];
#pragma unroll
    for (int i = 0; i < 4; ++i)
#pragma unroll
        for (int j = 0; j < 4; ++j) acc[i][j] = (f32x4)0.f;

    for (int kc = 0; kc < 256; kc += 32) {
        load_lds16(srcA + kc, ldsA0);
        load_lds16(srcA + kc + 16384, ldsA1);
        load_lds16(srcB + kc, ldsB0);
        load_lds16(srcB + kc + 16384, ldsB1);
        __syncthreads();

        bf16x8 af[4], bfr[4];
#pragma unroll
        for (int i = 0; i < 4; ++i) af[i]  = *(const bf16x8*)(abase + i * 1024);
#pragma unroll
        for (int j = 0; j < 4; ++j) bfr[j] = *(const bf16x8*)(bbase + j * 1024);
#pragma unroll
        for (int i = 0; i < 4; ++i)
#pragma unroll
            for (int j = 0; j < 4; ++j)
                acc[i][j] = __builtin_amdgcn_mfma_f32_16x16x32_bf16(
                    af[i], bfr[j], acc[i][j], 0, 0, 0);
        __syncthreads();
    }

    if (mode == 0) {
        if (mw == 0) {
            __bf16* dbase = dstT + (long)mb * (NPIX * 32);
#pragma unroll
            for (int fi = 0; fi < 2; ++fi)
#pragma unroll
                for (int r = 0; r < 4; ++r) {
                    int oc = 16 * fi + quad * 4 + r;
                    float bi = bias[oc];
#pragma unroll
                    for (int fj = 0; fj < 4; ++fj) {
                        int n = n0 + nw + 16 * fj + l15;
                        dbase[(long)n * 32 + oc] = f2b((acc[fi][fj][r] + bi) * oscale);
                    }
                }
        }
    } else if (mode == 1) {
        __bf16* dv = dstV + (long)mb * (256 * NPIX);
#pragma unroll
        for (int fi = 0; fi < 4; ++fi)
#pragma unroll
            for (int r = 0; r < 4; ++r) {
                int c = m0 + mw + 16 * fi + quad * 4 + r;
                float bi = bias[c];
                __bf16* row = dv + (long)c * NPIX;
#pragma unroll
                for (int fj = 0; fj < 4; ++fj) {
                    int n = n0 + nw + 16 * fj + l15;
                    row[n] = f2b(acc[fi][fj][r] + bi);
                }
            }
    } else {
        float* du = dstU + (long)mod * 4194304 + (long)b * 2097152;
        const float* rs = (mod ? resid_d : resid_r) + (long)b * 2097152;
#pragma unroll
        for (int fi = 0; fi < 4; ++fi)
#pragma unroll
            for (int r = 0; r < 4; ++r) {
                int oc = m0 + mw + 16 * fi + quad * 4 + r;
                float bi = bias[oc];
                const float* rrow = rs + (long)oc * NPIX;
                float* orow = du + (long)oc * NPIX;
#pragma unroll
                for (int fj = 0; fj < 4; ++fj) {
                    int n = n0 + nw + 16 * fj + l15;
                    orow[n] = acc[fi][fj][r] + bi + rrow[n];
                }
            }
    }
}

// ---------------------------------------------------------------------------
// MAX-ONLY MFMA row stats over a j-SEGMENT [seg*1024, +1024): partial m.
// grid (32 i, 4 mbo, 4 seg) = 512 blocks.
// ---------------------------------------------------------------------------
__global__ __launch_bounds__(256)
void attn_stats_mfma(const __bf16* __restrict__ Qt, const __bf16* __restrict__ Kt,
                     float* __restrict__ rmp)
{
    __shared__ __bf16 Qs[128 * 32];
    __shared__ __bf16 Ks[128 * 32];
    __shared__ float redm[2][128];

    const int t  = threadIdx.x;
    const int i0 = blockIdx.x * 128;
    const int mbo = blockIdx.y;
    const int o  = mbo >> 1, b = mbo & 1;
    const int seg = blockIdx.z;
    const int jbase = seg * 1024;
    const int mbK = o * 2 + b, mbQ = (1 - o) * 2 + b;

    const __bf16* Qg = Qt + (long)mbQ * 131072;
    const __bf16* Kg = Kt + (long)mbK * 131072;

    const int lane = t & 63, quad = lane >> 4, l15 = lane & 15, w = t >> 6;
    const int mS = (w >> 1) * 64;
    const int nS = (w & 1) * 64;

    const int drow = w * 16 + (lane >> 2);                  // staging dest row
    const int ssl  = ((lane & 3) ^ ((lane >> 3) & 3)) * 16; // swizzled src slot
    const int rsl  = (quad ^ ((l15 >> 1) & 3)) << 4;        // swizzled read slot

    load_lds16((const char*)Qg + (long)(i0 + drow) * 64 + ssl, (char*)Qs + w * 1024);
    load_lds16((const char*)Qg + (long)(i0 + 64 + drow) * 64 + ssl,
               (char*)Qs + 4096 + w * 1024);
    __syncthreads();

    bf16x8 qa[4];
#pragma unroll
    for (int fi = 0; fi < 4; ++fi)
        qa[fi] = *(const bf16x8*)((const char*)Qs + (mS + 16 * fi + l15) * 64 + rsl);

    const f32x4 zero4 = (f32x4)0.f;
    float m_t[16];
#pragma unroll
    for (int e = 0; e < 16; ++e) m_t[e] = -3.0e38f;

    for (int j0 = jbase; j0 < jbase + 1024; j0 += 128) {
        __syncthreads();
        load_lds16((const char*)Kg + (long)(j0 + drow) * 64 + ssl, (char*)Ks + w * 1024);
        load_lds16((const char*)Kg + (long)(j0 + 64 + drow) * 64 + ssl,
                   (char*)Ks + 4096 + w * 1024);
        __syncthreads();

        bf16x8 kb[4];
#pragma unroll
        for (int fj = 0; fj < 4; ++fj)
            kb[fj] = *(const bf16x8*)((const char*)Ks + (nS + 16 * fj + l15) * 64 + rsl);
#pragma unroll
        for (int fi = 0; fi < 4; ++fi) {
            f32x4 sf[4];
#pragma unroll
            for (int fj = 0; fj < 4; ++fj)
                sf[fj] = __builtin_amdgcn_mfma_f32_16x16x32_bf16(qa[fi], kb[fj], zero4, 0, 0, 0);
#pragma unroll
            for (int r = 0; r < 4; ++r) {
                int e = fi * 4 + r;
                float a = fmaxf(fmaxf(sf[0][r], sf[1][r]), fmaxf(sf[2][r], sf[3][r]));
                m_t[e] = fmaxf(m_t[e], a);
            }
        }
    }

#pragma unroll
    for (int d = 1; d < 16; d <<= 1)
#pragma unroll
        for (int e = 0; e < 16; ++e)
            m_t[e] = fmaxf(m_t[e], __shfl_xor(m_t[e], d, 64));
    if (l15 == 0) {
#pragma unroll
        for (int fi = 0; fi < 4; ++fi)
#pragma unroll
            for (int r = 0; r < 4; ++r)
                redm[w & 1][mS + 16 * fi + quad * 4 + r] = m_t[fi * 4 + r];
    }
    __syncthreads();
    if (t < 128)
        rmp[seg * 16384 + mbo * 4096 + i0 + t] = fmaxf(redm[0][t], redm[1][t]);
}

// ---------------------------------------------------------------------------
// Merge 4-segment maxes: rmb = max_s rmp[s]. grid 64 x 256.
// ---------------------------------------------------------------------------
__global__ __launch_bounds__(256)
void stats_merge(const float* __restrict__ rmp, float* __restrict__ rmb)
{
    int idx = blockIdx.x * 256 + threadIdx.x;
    float m = rmp[idx];
#pragma unroll
    for (int s = 1; s < 4; ++s) m = fmaxf(m, rmp[s * 16384 + idx]);
    rmb[idx] = m;
}

// ---------------------------------------------------------------------------
// Fused MFMA PV (round-16 version, byte-exact): v4 staging (3 barriers,
// 2 blocks/CU, XCD grouping, conflict-free swizzles); l accumulated in the
// P phase on the f32 p values (lsum[r] += p), butterfly at the end; raw acc
// stored (normalize in zred).
// ---------------------------------------------------------------------------
__global__ __launch_bounds__(256, 2)
void attn_pv_mfma(const __bf16* __restrict__ Qt, const __bf16* __restrict__ Kt,
                  const __bf16* __restrict__ Vb,
                  float* __restrict__ part0, float* __restrict__ part1,
                  const float* __restrict__ rmb, float* __restrict__ lbuf)
{
    __shared__ __bf16 Qs[64 * 32];        // 4KB  [64 i][32ch]
    __shared__ __bf16 Ks[64 * 32];        // 4KB  [64 j][32ch]
    __shared__ __bf16 Vs[2 * 256 * 32];   // 32KB [2ks][256c][32j]
    __shared__ __bf16 Ps[64 * 64];        // 8KB  [64 i][64 j] swizzled

    const int t  = threadIdx.x;
    const int bx = blockIdx.x;
    const int grp = bx & 7;               // XCD group = (mb<<1)|seg
    const int i0  = (bx >> 3) * 64;
    const int seg = grp & 1;
    const int mb  = grp >> 1;
    const int o  = mb >> 1, b = mb & 1;
    const int mbQ = (1 - o) * 2 + b;
    const int jbase = seg * 2048;

    const __bf16* Qg = Qt + (long)mbQ * 131072;
    const __bf16* Kg = Kt + (long)mb * 131072;
    const __bf16* Vg = Vb + (long)mb * 1048576;
    const float* rm = rmb + mb * 4096;

    const int lane = t & 63, quad = lane >> 4, l15 = lane & 15, w = t >> 6;
    const int iS = w * 16;                // this wave's S row block
    const int cw = w * 64;                // this wave's PV c block

    const int drow = w * 16 + (lane >> 2);                  // staging dest row
    const int ssl  = ((lane & 3) ^ ((lane >> 3) & 3)) * 16; // swizzled src slot
    const int rsl  = (quad ^ ((l15 >> 1) & 3)) << 4;        // swizzled read slot

    // Q stage (64 rows, 4KB)
    load_lds16((const char*)Qg + (long)(i0 + drow) * 64 + ssl, (char*)Qs + w * 1024);

    float mlv[4], lsum[4];
#pragma unroll
    for (int r = 0; r < 4; ++r) { mlv[r] = rm[i0 + iS + quad * 4 + r]; lsum[r] = 0.f; }

    f32x4 acc[4][4];
#pragma unroll
    for (int i = 0; i < 4; ++i)
#pragma unroll
        for (int j = 0; j < 4; ++j) acc[i][j] = (f32x4)0.f;
    const f32x4 zero4 = (f32x4)0.f;

    __syncthreads();
    const bf16x8 qa = *(const bf16x8*)((const char*)Qs + (iS + l15) * 64 + rsl);

    for (int j0 = jbase; j0 < jbase + 2048; j0 += 64) {
        __syncthreads();                    // prev-step consumers done
        load_lds16((const char*)Kg + (long)(j0 + drow) * 64 + ssl,
                   (char*)Ks + w * 1024);
        __syncthreads();                    // K ready (only K in flight)

        // issue V loads now; latency hides under S + P (drained at next barrier)
#pragma unroll
        for (int ii = 0; ii < 8; ++ii) {
            int ks = ii >> 2;
            int c  = (ii & 3) * 64 + drow;
            load_lds16((const char*)Vg + (long)c * 8192 + (long)(j0 + ks * 32) * 2 + ssl,
                       (char*)Vs + ii * 4096 + w * 1024);
        }

        // S = Q K^T for rows [iS,iS+16), cols [0,64)
        f32x4 sA[4];
#pragma unroll
        for (int fj = 0; fj < 4; ++fj) {
            bf16x8 kb = *(const bf16x8*)((const char*)Ks + (16 * fj + l15) * 64 + rsl);
            sA[fj] = __builtin_amdgcn_mfma_f32_16x16x32_bf16(qa, kb, zero4, 0, 0, 0);
        }
        // P = exp2(S - m) -> swizzled Ps; lsum accumulates the same floats
#pragma unroll
        for (int fj = 0; fj < 4; ++fj)
#pragma unroll
            for (int r = 0; r < 4; ++r) {
                int il = iS + quad * 4 + r;
                float p = exp2f(sA[fj][r] - mlv[r]);
                lsum[r] += p;
                int boff = (il * 128 + (16 * fj + l15) * 2) ^ ((il & 7) << 4);
                *(__bf16*)((char*)Ps + boff) = f2b(p);
            }
        __syncthreads();                    // P visible, V staged

#pragma unroll
        for (int ks = 0; ks < 2; ++ks) {
            bf16x8 va[4], pb[4];
#pragma unroll
            for (int fi = 0; fi < 4; ++fi)
                va[fi] = *(const bf16x8*)((const char*)Vs + ks * 16384 +
                                          (cw + 16 * fi + l15) * 64 + rsl);
#pragma unroll
            for (int fj = 0; fj < 4; ++fj) {
                int ip = 16 * fj + l15;
                int boff = (ip * 128 + ks * 64 + quad * 16) ^ ((ip & 7) << 4);
                pb[fj] = *(const bf16x8*)((const char*)Ps + boff);
            }
#pragma unroll
            for (int fi = 0; fi < 4; ++fi)
#pragma unroll
                for (int fj = 0; fj < 4; ++fj)
                    acc[fi][fj] = __builtin_amdgcn_mfma_f32_16x16x32_bf16(
                        va[fi], pb[fj], acc[fi][fj], 0, 0, 0);
        }
    }

    // raw partial store (merge/normalize in zred)
    float* pg = (seg ? part1 : part0) + (long)mb * 1048576;
#pragma unroll
    for (int fi = 0; fi < 4; ++fi) {
#pragma unroll
        for (int r = 0; r < 4; ++r) {
            int c = cw + 16 * fi + quad * 4 + r;
            float* zr = pg + (long)c * 4096;
#pragma unroll
            for (int fj = 0; fj < 4; ++fj)
                zr[i0 + 16 * fj + l15] = acc[fi][fj][r];
        }
    }

    // l: butterfly across the 16 l15 lanes (disjoint j-columns), store per row
#pragma unroll
    for (int d = 1; d < 16; d <<= 1)
#pragma unroll
        for (int r = 0; r < 4; ++r)
            lsum[r] += __shfl_xor(lsum[r], d, 64);
    if (l15 == 0) {
        float* lb = lbuf + seg * 16384 + mb * 4096;
#pragma unroll
        for (int r = 0; r < 4; ++r)
            lb[i0 + iS + quad * 4 + r] = lsum[r];
    }
}

// ---------------------------------------------------------------------------
// z = (gamma/(l0+l1))*(part0+part1) + conv(Ct bf16), transposed bf16 store.
// grid (128, 8, 4). Conv residual added POST-transpose from Ct[pix][256].
// ---------------------------------------------------------------------------
__global__ __launch_bounds__(256)
void zred_t(const float* __restrict__ p0, const float* __restrict__ p1,
            const __bf16* __restrict__ Ct, __bf16* __restrict__ Zt,
            const float* __restrict__ g_r, const float* __restrict__ g_d,
            const float* __restrict__ lbuf)
{
    __shared__ float tile[32][33];
    const int t = threadIdx.x;
    const int pix0 = blockIdx.x * 32;
    const int c0 = blockIdx.y * 32;
    const int mb = blockIdx.z;
    const int o = mb >> 1;
    const float gamma = (o ? g_d : g_r)[0];
    const long base = (long)mb * 1048576;

    int i = t >> 3, j4 = (t & 7) * 4;
    const float* l0p = lbuf + mb * 4096;
    const float* l1p = lbuf + 16384 + mb * 4096;
    float4 la = *(const float4*)&l0p[pix0 + j4];
    float4 lc = *(const float4*)&l1p[pix0 + j4];
    float g0 = gamma / (la.x + lc.x);
    float g1 = gamma / (la.y + lc.y);
    float g2 = gamma / (la.z + lc.z);
    float g3 = gamma / (la.w + lc.w);

    long row = base + (long)(c0 + i) * 4096 + pix0 + j4;
    float4 a = *(const float4*)&p0[row];
    float4 b = *(const float4*)&p1[row];
    tile[i][j4 + 0] = g0 * (a.x + b.x);
    tile[i][j4 + 1] = g1 * (a.y + b.y);
    tile[i][j4 + 2] = g2 * (a.z + b.z);
    tile[i][j4 + 3] = g3 * (a.w + b.w);
    __syncthreads();
    int j = t >> 3, i4 = (t & 7) * 4;
    bf16x4 cv = *(const bf16x4*)&Ct[(long)mb * NPIX * 256 +
                                    (long)(pix0 + j) * 256 + c0 + i4];
    bf16x4 oq;
    oq.x = f2b(tile[i4 + 0][j] + (float)cv.x);
    oq.y = f2b(tile[i4 + 1][j] + (float)cv.y);
    oq.z = f2b(tile[i4 + 2][j] + (float)cv.z);
    oq.w = f2b(tile[i4 + 3][j] + (float)cv.w);
    *(bf16x4*)&Zt[(long)mb * NPIX * 256 + (long)(pix0 + j) * 256 + c0 + i4] = oq;
}

// ---------------------------------------------------------------------------
// Host launcher
// ---------------------------------------------------------------------------
extern "C" void kernel_launch(void* const* d_in, const int* in_sizes, int n_in,
                              void* d_out, int out_size, void* d_ws, size_t ws_size,
                              hipStream_t stream)
{
    const float* in_rgb = (const float*)d_in[0];
    const float* in_dsm = (const float*)d_in[1];
    auto P = [&](int i) { return (const float*)d_in[i]; };

    float* ws    = (float*)d_ws;
    float* part0 = ws + 4194304;
    float* rmb   = ws + 8388608;
    float* lbuf  = ws + 8421376;
    float* rmp   = part0;            // [4seg][4][4096] scratch, dead before pv
    float* scA   = ws + 8486912;
    float* shB   = ws + 8487424;
    __bf16* zrow = (__bf16*)(ws + 8487936);
    __bf16* Wt   = (__bf16*)(ws + 8488192);
    __bf16* Xp   = (__bf16*)(ws + 9667840);
    float*  part1 = ws + 9667840;            // aliases Xp (dead after conv)
    __bf16* Qt   = (__bf16*)(ws + 13862144);
    __bf16* Kt   = (__bf16*)(ws + 14124288);
    __bf16* Vbb  = (__bf16*)(ws + 14386432);
    __bf16* Ct   = (__bf16*)(ws + 16483584);
    __bf16* Zt   = (__bf16*)(ws + 18580736);
    __bf16* Wq   = (__bf16*)(ws + 20677888);
    __bf16* Wk   = (__bf16*)(ws + 20710656);
    __bf16* Wv   = (__bf16*)(ws + 20743424);
    __bf16* Wu   = (__bf16*)(ws + 20808960);

    // prep
    prep_w<<<2307, 256, 0, stream>>>(
        P(2), P(18), P(3), P(4), P(5), P(6), P(7),
        P(19), P(20), P(21), P(22), P(23),
        Wt, scA, shB, zrow);
    prep_gw<<<512, 256, 0, stream>>>(
        P(9), P(25), P(11), P(27), P(13), P(29), P(15), P(31),
        Wq, Wk, Wv, Wu);
    xpose<<<dim3(128, 16, 4), 256, 0, stream>>>(in_rgb, in_dsm, Xp);

    // conv3x3 + BN + PReLU -> Ct bf16 [pix][256] directly
    conv_mfma<<<dim3(16, 4, 4), 512, 0, stream>>>(
        Wt, Xp, zrow, scA, shB, P(8), P(24), Ct);

    // q/k/v projections (Q pre-scaled by log2e -> exp2 softmax domain)
    proj_mfma<<<dim3(32, 1, 4), 256, 0, stream>>>(
        Wq, 32768, Ct, P(10), P(26), Qt, nullptr, nullptr, nullptr, nullptr,
        0, 1.4426950408889634f);
    proj_mfma<<<dim3(32, 1, 4), 256, 0, stream>>>(
        Wk, 32768, Ct, P(12), P(28), Kt, nullptr, nullptr, nullptr, nullptr,
        0, 1.0f);
    proj_mfma<<<dim3(32, 2, 4), 256, 0, stream>>>(
        Wv, 65536, Ct, P(14), P(30), nullptr, Vbb, nullptr, nullptr, nullptr,
        1, 1.0f);

    // max-only stats (j-split x4, 512 blocks) + max merge
    attn_stats_mfma<<<dim3(32, 4, 4), 256, 0, stream>>>(Qt, Kt, rmp);
    stats_merge<<<64, 256, 0, stream>>>(rmp, rmb);

    // fused PV (r16 version: l in P phase, raw partials)
    attn_pv_mfma<<<512, 256, 0, stream>>>(
        Qt, Kt, Vbb, part0, part1, rmb, lbuf);

    // z = (gamma/(l0+l1))*(p0+p1) + Ct, transpose + bf16 -> Zt
    zred_t<<<dim3(128, 8, 4), 256, 0, stream>>>(
        part0, part1, Ct, Zt, P(17), P(33), lbuf);

    // up projection + input residual -> fp32 out
    proj_mfma<<<dim3(32, 4, 4), 256, 0, stream>>>(
        Wu, 131072, Zt, P(16), P(32), nullptr, nullptr, (float*)d_out,
        in_rgb, in_dsm, 2, 1.0f);
}